// Round 9
// baseline (691.791 us; speedup 1.0000x reference)
//
#include <hip/hip_runtime.h>
#include <math.h>

typedef unsigned short ushortT;
typedef __attribute__((ext_vector_type(8))) short short8;
typedef __attribute__((ext_vector_type(4))) float f32x4;

#define NN 4096
#define DD 1024
#define NC 100
#define CP 128
#define NLAB 2048
#define NITER 30

__device__ __forceinline__ ushortT bf16rn(float x) {
  unsigned u = __float_as_uint(x);
  unsigned r = (u + 0x7fffu + ((u >> 16) & 1u)) >> 16;
  return (ushortT)r;
}
__device__ __forceinline__ float bf2f(ushortT h) {
  return __uint_as_float(((unsigned)h) << 16);
}
__device__ __forceinline__ void gload16(const void* g, void* l) {
  __builtin_amdgcn_global_load_lds((const __attribute__((address_space(1))) char*)g,
                                   (__attribute__((address_space(3))) char*)l, 16, 0, 0);
}

// ---------------- normalize rows -> bf16 hi/lo splits ----------------
__global__ __launch_bounds__(256) void k_normalize(const float* __restrict__ E,
                                                   ushortT* __restrict__ Enh,
                                                   ushortT* __restrict__ Enl) {
  int row = blockIdx.x, t = threadIdx.x;
  const float4* e4 = (const float4*)(E + (size_t)row * DD);
  float4 v = e4[t];
  float ss = v.x * v.x + v.y * v.y + v.z * v.z + v.w * v.w;
  __shared__ float red[4];
  int lane = t & 63, w = t >> 6;
#pragma unroll
  for (int off = 32; off; off >>= 1) ss += __shfl_xor(ss, off);
  if (lane == 0) red[w] = ss;
  __syncthreads();
  float tot = red[0] + red[1] + red[2] + red[3];
  float d = fmaxf(sqrtf(tot), 1e-12f);
  float xs[4] = {v.x / d, v.y / d, v.z / d, v.w / d};
  ushort4 hv, lv;
  ushortT h;
  h = bf16rn(xs[0]); hv.x = h; lv.x = bf16rn(xs[0] - bf2f(h));
  h = bf16rn(xs[1]); hv.y = h; lv.y = bf16rn(xs[1] - bf2f(h));
  h = bf16rn(xs[2]); hv.z = h; lv.z = bf16rn(xs[2] - bf2f(h));
  h = bf16rn(xs[3]); hv.w = h; lv.w = bf16rn(xs[3] - bf2f(h));
  ((ushort4*)Enh)[(size_t)row * 256 + t] = hv;
  ((ushort4*)Enl)[(size_t)row * 256 + t] = lv;
}

// ---------------- A0 = relu(En@En^T) via MFMA, 3-term bf16 split; diag=1 ----------------
// Upper-tri tiles, XCD-pinned bi-bands; grid 640 (pad blocks exit).
__global__ __launch_bounds__(256, 2) void k_syrk_mfma(const ushortT* __restrict__ Enh,
                                                      const ushortT* __restrict__ Enl,
                                                      float* __restrict__ A) {
  int xg = (int)blockIdx.x & 7;
  int j = (int)blockIdx.x >> 3;  // 0..79
  int bi = -1, bj = 0;
#pragma unroll
  for (int p = 0; p < 4; ++p) {
    int bic = xg + (p << 3);
    int c = 32 - bic;
    if (bi < 0) {
      if (j < c) { bi = bic; bj = bic + j; } else j -= c;
    }
  }
  if (bi < 0) return;
  __shared__ ushortT lds[2][16384];
  int t = threadIdx.x;
  int l = t & 63, w = t >> 6;
  int i0 = bi << 7, j0 = bj << 7;
  int wr = w >> 1, wc = w & 1;
  f32x4 zz = {0.f, 0.f, 0.f, 0.f};
  f32x4 acc[4][4];
#pragma unroll
  for (int m = 0; m < 4; ++m)
#pragma unroll
    for (int n = 0; n < 4; ++n) acc[m][n] = zz;
  int arow_l = l & 15, kslot = l >> 4;

  auto stage = [&](int b, int s) {
    int term = s >> 4;
    int kk0 = (s & 15) << 6;
    const ushortT* sa = (term == 2) ? Enl : Enh;
    const ushortT* sb = (term == 1) ? Enl : Enh;
#pragma unroll
    for (int q = 0; q < 4; ++q) {
      int n = (q << 8) + t;
      int r = n >> 3, p = n & 7;
      int col = (p ^ (r & 7)) << 3;
      gload16(sa + (size_t)(i0 + r) * DD + kk0 + col, &lds[b][n << 3]);
      gload16(sb + (size_t)(j0 + r) * DD + kk0 + col, &lds[b][8192 + (n << 3)]);
    }
  };

  stage(0, 0);
  int cur = 0;
  for (int s = 0; s < 48; ++s) {
    if (s < 47) {
      stage(cur ^ 1, s + 1);
      asm volatile("s_waitcnt vmcnt(8)" ::: "memory");
    } else {
      asm volatile("s_waitcnt vmcnt(0)" ::: "memory");
    }
    __builtin_amdgcn_s_barrier();
#pragma unroll
    for (int kk = 0; kk < 2; ++kk) {
      int g = (kk << 2) + kslot;
      short8 av[4], bv[4];
#pragma unroll
      for (int m = 0; m < 4; ++m) {
        int r = (wr << 6) + (m << 4) + arow_l;
        av[m] = *(const short8*)&lds[cur][(r << 6) + ((g ^ (r & 7)) << 3)];
      }
#pragma unroll
      for (int n = 0; n < 4; ++n) {
        int r = (wc << 6) + (n << 4) + arow_l;
        bv[n] = *(const short8*)&lds[cur][8192 + (r << 6) + ((g ^ (r & 7)) << 3)];
      }
#pragma unroll
      for (int m = 0; m < 4; ++m)
#pragma unroll
        for (int n = 0; n < 4; ++n)
          acc[m][n] = __builtin_amdgcn_mfma_f32_16x16x32_bf16(av[m], bv[n], acc[m][n], 0, 0, 0);
    }
    asm volatile("s_waitcnt lgkmcnt(0)" ::: "memory");
    __builtin_amdgcn_s_barrier();
    cur ^= 1;
  }
  int rbase = (l >> 4) << 2;
#pragma unroll
  for (int m = 0; m < 4; ++m) {
#pragma unroll
    for (int n = 0; n < 4; ++n) {
#pragma unroll
      for (int r = 0; r < 4; ++r) {
        int gi = i0 + (wr << 6) + (m << 4) + rbase + r;
        int gj = j0 + (wc << 6) + (n << 4) + (l & 15);
        float v = fmaxf(acc[m][n][r], 0.0f);
        if (gi == gj) v = 1.0f;
        A[(size_t)gi * NN + gj] = v;
      }
    }
  }
  if (bi != bj) {
    float* T = (float*)&lds[0][0];
#pragma unroll
    for (int c2 = 0; c2 < 2; ++c2) {
      __syncthreads();
      if (wr == c2) {
#pragma unroll
        for (int m = 0; m < 4; ++m)
#pragma unroll
          for (int n = 0; n < 4; ++n)
#pragma unroll
            for (int r = 0; r < 4; ++r)
              T[(((wc << 6) + (n << 4) + (l & 15)) * 68) + (m << 4) + rbase + r] =
                  fmaxf(acc[m][n][r], 0.0f);
      }
      __syncthreads();
      int lj = t >> 1, cg = (t & 1) << 5;
#pragma unroll
      for (int q = 0; q < 8; ++q) {
        float4 vq = *(const float4*)&T[lj * 68 + cg + (q << 2)];
        *(float4*)&A[(size_t)(j0 + lj) * NN + i0 + (c2 << 6) + cg + (q << 2)] = vq;
      }
    }
  }
}

// ---------------- sigma[i] = 7th largest of row i ----------------
__device__ __forceinline__ void ins7(float (&tv)[7], float v) {
  if (v > tv[6]) {
#pragma unroll
    for (int s = 0; s < 7; s++) {
      if (v > tv[s]) { float tmp = tv[s]; tv[s] = v; v = tmp; }
    }
  }
}
__global__ __launch_bounds__(256) void k_top7(const float* __restrict__ A,
                                              float* __restrict__ sig) {
  int w = threadIdx.x >> 6, lane = threadIdx.x & 63;
  int row = (blockIdx.x << 2) + w;
  const float4* a4 = (const float4*)(A + (size_t)row * NN);
  float tv[7];
#pragma unroll
  for (int i = 0; i < 7; i++) tv[i] = -1.0f;
  for (int k = 0; k < 16; k++) {
    float4 v = a4[(k << 6) + lane];
    ins7(tv, v.x); ins7(tv, v.y); ins7(tv, v.z); ins7(tv, v.w);
  }
  int head = 0;
  float seventh = 0.0f;
  for (int r = 0; r < 7; r++) {
    float h = (head < 7) ? tv[head] : -1.0f;
    float m = h;
#pragma unroll
    for (int off = 32; off; off >>= 1) m = fmaxf(m, __shfl_xor(m, off));
    unsigned long long ball = __ballot(h == m);
    if (lane == (__ffsll(ball) - 1)) head++;
    seventh = m;
  }
  if (lane == 0) sig[row] = seventh;
}

// ---------------- mean pass: sum exp(-(A^2)/(si*sj)) per row, no store ----------------
__global__ __launch_bounds__(256) void k_transform(const float* __restrict__ A,
                                                   const float* __restrict__ sig,
                                                   double* __restrict__ parts) {
  int row = blockIdx.x;
  float si = sig[row];
  const float4* a4 = (const float4*)(A + (size_t)row * NN);
  const float4* s4 = (const float4*)sig;
  int t = threadIdx.x;
  double local = 0.0;
#pragma unroll
  for (int k = 0; k < 4; k++) {
    int j = (k << 8) + t;
    float4 v = a4[j];
    float4 sg = s4[j];
    local += (double)expf(-(v.x * v.x) / (si * sg.x)) +
             (double)expf(-(v.y * v.y) / (si * sg.y)) +
             (double)expf(-(v.z * v.z) / (si * sg.z)) +
             (double)expf(-(v.w * v.w) / (si * sg.w));
  }
  __shared__ double dred[4];
  int lane = t & 63, wv = t >> 6;
#pragma unroll
  for (int off = 32; off; off >>= 1) local += __shfl_xor(local, off);
  if (lane == 0) dred[wv] = local;
  __syncthreads();
  if (t == 0) parts[row] = dred[0] + dred[1] + dred[2] + dred[3];
}

__global__ __launch_bounds__(256) void k_mean(const double* __restrict__ parts,
                                              float* __restrict__ meanb) {
  int t = threadIdx.x;
  double local = 0.0;
#pragma unroll
  for (int k = 0; k < NN / 256; k++) local += parts[(k << 8) + t];
  __shared__ double dred[4];
  int lane = t & 63, wv = t >> 6;
#pragma unroll
  for (int off = 32; off; off >>= 1) local += __shfl_xor(local, off);
  if (lane == 0) dred[wv] = local;
  __syncthreads();
  if (t == 0) meanb[0] = (float)((dred[0] + dred[1] + dred[2] + dred[3]) / ((double)NN * (double)NN));
}

// ---------------- thresh: recompute exp on bottom half, threshold, pack to Ap{L,U} ----
// Fragment-major pack: Ap[rt 128][kc 64][khi 4][arow 16][k0 8] bf16.
__global__ __launch_bounds__(256) void k_thresh_pack(const float* __restrict__ A,
                                                     const float* __restrict__ sig,
                                                     const float* __restrict__ meanb,
                                                     ushortT* __restrict__ ApL,
                                                     ushortT* __restrict__ ApU) {
  float m = meanb[0];
  int i4 = ((int)blockIdx.x << 8) + threadIdx.x;  // 2M over [2048][1024]
  int row2 = i4 >> 10;
  int col4 = (i4 & 1023) << 2;
  int grow = NLAB + row2;
  float si = sig[grow];
  float4 v = *(const float4*)&A[(size_t)grow * NN + col4];
  float4 sg = *(const float4*)&sig[col4];
  float c0 = expf(-(v.x * v.x) / (si * sg.x));
  float c1 = expf(-(v.y * v.y) / (si * sg.y));
  float c2 = expf(-(v.z * v.z) / (si * sg.z));
  float c3 = expf(-(v.w * v.w) / (si * sg.w));
  c0 = (c0 < m) ? 0.0f : c0;
  c1 = (c1 < m) ? 0.0f : c1;
  c2 = (c2 < m) ? 0.0f : c2;
  c3 = (c3 < m) ? 0.0f : c3;
  int half = col4 >> 11;
  int cc = col4 & 2047;
  int rt = row2 >> 4, arow = row2 & 15;
  int kc = cc >> 5, khi = (cc >> 3) & 3, k0 = cc & 7;
  ushortT* dst = half ? ApU : ApL;
  ushort4 hv;
  hv.x = bf16rn(c0); hv.y = bf16rn(c1); hv.z = bf16rn(c2); hv.w = bf16rn(c3);
  *(ushort4*)&dst[((size_t)((rt << 6) + kc) << 9) + (khi << 7) + (arow << 3) + k0] = hv;
}

// ---------------- one-hot labels, packed layout [kc][cf][khi][slot][k0] ----------------
__global__ __launch_bounds__(256) void k_xlabp(const int* __restrict__ labels,
                                               ushortT* __restrict__ Xlabp) {
  int idx = ((int)blockIdx.x << 8) + threadIdx.x;  // 262144
  int c = idx >> 11, j = idx & 2047;
  int kc = j >> 5, khi = (j >> 3) & 3, k0 = j & 7;
  int cf = c >> 4, slot = c & 15;
  Xlabp[((size_t)(((kc << 3) + cf) << 2) + khi) * 128 + (slot << 3) + k0] =
      (labels[j] == c) ? (ushortT)0x3F80 : (ushortT)0;
}

// ---------------- X init: fragment-major Xf f32 + packed Xp bf16 ----------------
__global__ __launch_bounds__(64) void k_xinit(float* __restrict__ Xf,
                                              ushortT* __restrict__ Xp) {
  int rt = blockIdx.x, l = threadIdx.x;
  int col = l & 15, rg4 = l >> 4;
  int kc = rt >> 1;
  int kk = ((rt & 1) << 4) + (rg4 << 2);
  int khi = kk >> 3, k0 = kk & 7;
#pragma unroll
  for (int cf = 0; cf < 8; ++cf) {
    int cls = (cf << 4) + col;
    float v = (cls < NC) ? 0.01f : 0.0f;
    ((f32x4*)Xf)[(size_t)((rt << 3) + cf) * 64 + l] = (f32x4){v, v, v, v};
    ushortT h = bf16rn(v);
    ushort4 hv = {h, h, h, h};
    *(ushort4*)&Xp[((size_t)(((kc << 3) + cf) << 2) + khi) * 128 + (col << 3) + k0] = hv;
  }
}

// ---------------- fused iteration: GEMM (8-wave K-split) + LDS reduce + update ----
// 128 blocks x 512 thr; block = rt tile (16 rows); wave w = K-slice of 8 kc.
// All global loads wave-contiguous 1 KB. One kernel per iteration.
template <bool UPDATE>
__global__ __launch_bounds__(512) void k_iterF(
    const ushortT* __restrict__ Ap,   // packed [128 rt][64 kc][512]
    const ushortT* __restrict__ Xp,   // packed [64 kc][8 cf][512]
    const float* __restrict__ YlabF,  // frag-major (UPDATE)
    const float* __restrict__ XfPrev, // frag-major (UPDATE)
    float* __restrict__ XfOut,        // frag-major
    ushortT* __restrict__ XpOut) {    // packed (UPDATE)
  __shared__ float part[8][8][64][4];  // [wp][cf][lane][reg] = 64 KB
  __shared__ float sums[8][16];
  int t = threadIdx.x, l = t & 63, w = t >> 6;
  int bid = (int)blockIdx.x;
  int rt = ((bid & 7) << 4) + (bid >> 3);  // XCD-pinned row tiles

  const ushortT* ab = Ap + ((size_t)rt << 15) + ((size_t)w << 12) + (l << 3);
  const ushortT* xb = Xp + ((size_t)w << 15) + (l << 3);
  short8 av[8];
#pragma unroll
  for (int i = 0; i < 8; ++i) av[i] = *(const short8*)(ab + ((size_t)i << 9));
  f32x4 acc[8];
#pragma unroll
  for (int cf = 0; cf < 8; ++cf) {
    acc[cf] = (f32x4){0.f, 0.f, 0.f, 0.f};
#pragma unroll
    for (int i = 0; i < 8; ++i) {
      short8 bv = *(const short8*)(xb + ((size_t)i << 12) + (cf << 9));
      acc[cf] = __builtin_amdgcn_mfma_f32_16x16x32_bf16(av[i], bv, acc[cf], 0, 0, 0);
    }
  }
#pragma unroll
  for (int cf = 0; cf < 8; ++cf)
    *(f32x4*)&part[w][cf][l][0] = acc[cf];
  __syncthreads();

  // wave w reduces cf = w across the 8 K-slices
  f32x4 mm = (f32x4){0.f, 0.f, 0.f, 0.f};
#pragma unroll
  for (int wp = 0; wp < 8; ++wp) {
    f32x4 p = *(const f32x4*)&part[wp][w][l][0];
    mm[0] += p[0]; mm[1] += p[1]; mm[2] += p[2]; mm[3] += p[3];
  }
  size_t fo = (size_t)((rt << 3) + w) * 64 + l;
  if constexpr (!UPDATE) {
    ((f32x4*)XfOut)[fo] = mm;
  } else {
    f32x4 yl = ((const f32x4*)YlabF)[fo];
    f32x4 xv = ((const f32x4*)XfPrev)[fo];
    f32x4 mult, rs;
#pragma unroll
    for (int r = 0; r < 4; ++r) {
      mult[r] = fmaf(xv[r], mm[r] + yl[r], xv[r]);
      rs[r] = mult[r];
    }
#pragma unroll
    for (int msk = 1; msk < 16; msk <<= 1) {
#pragma unroll
      for (int r = 0; r < 4; ++r) rs[r] += __shfl_xor(rs[r], msk);
    }
    int rg4 = l >> 4, col16 = l & 15;
    if (col16 == 0) {
#pragma unroll
      for (int r = 0; r < 4; ++r) sums[w][(rg4 << 2) + r] = rs[r];
    }
    __syncthreads();
    f32x4 tot;
#pragma unroll
    for (int r = 0; r < 4; ++r) {
      float s = 1e-8f;
#pragma unroll
      for (int w2 = 0; w2 < 8; ++w2) s += sums[w2][(rg4 << 2) + r];
      tot[r] = s;
    }
    f32x4 ov;
#pragma unroll
    for (int r = 0; r < 4; ++r) ov[r] = mult[r] / tot[r];
    ((f32x4*)XfOut)[fo] = ov;
    int kcp = rt >> 1;
    int rem = ((rt & 1) << 4) + (rg4 << 2);
    int khi = rem >> 3, k0 = rem & 7;
    ushort4 xo;
    xo.x = bf16rn(ov[0]); xo.y = bf16rn(ov[1]);
    xo.z = bf16rn(ov[2]); xo.w = bf16rn(ov[3]);
    *(ushort4*)&XpOut[((size_t)(((kcp << 3) + w) << 2) + khi) * 128 + (col16 << 3) + k0] = xo;
  }
}

// ---------------- output assembly (reads fragment-major Xf) ----------------
__global__ __launch_bounds__(256) void k_output(const float* __restrict__ Xf,
                                                const int* __restrict__ labels,
                                                float* __restrict__ out) {
  int idx = ((int)blockIdx.x << 8) + threadIdx.x;  // 409600
  int i = idx / NC, c = idx - i * NC;
  float v;
  if (i < NLAB) {
    v = (labels[i] == c) ? 1.0f : 0.0f;
  } else {
    int row = i - NLAB;
    int rt = row >> 4, r = row & 15;
    int rg4 = r >> 2, reg = r & 3;
    int cf = c >> 4, col = c & 15;
    v = Xf[((size_t)(((rt << 3) + cf) << 6) + (rg4 << 4) + col) * 4 + reg];
  }
  out[idx] = v;
}

extern "C" void kernel_launch(void* const* d_in, const int* in_sizes, int n_in,
                              void* d_out, int out_size, void* d_ws, size_t ws_size,
                              hipStream_t stream) {
  const float* E = (const float*)d_in[0];
  const int* labels = (const int*)d_in[1];
  float* out = (float*)d_out;
  char* ws = (char*)d_ws;
  const size_t MB = 1024 * 1024;

  float* A = (float*)ws;                          // 64 MB
  ushortT* Enh = (ushortT*)(ws + 64 * MB);        // 8 MB
  ushortT* Enl = (ushortT*)(ws + 72 * MB);        // 8 MB
  ushortT* ApL = (ushortT*)(ws + 80 * MB);        // 8 MB packed A[:, :2048]
  ushortT* ApU = (ushortT*)(ws + 88 * MB);        // 8 MB packed A[:, 2048:]
  float* sig = (float*)(ws + 96 * MB);
  double* parts = (double*)(ws + 96 * MB + 65536);
  float* meanb = (float*)(ws + 96 * MB + 131072);
  ushortT* Xlabp = (ushortT*)(ws + 97 * MB);      // 0.5 MB packed
  float* YlabF = (float*)(ws + 98 * MB);          // 1 MB frag-major
  float* Xf0 = (float*)(ws + 99 * MB);            // 1 MB frag-major
  float* Xf1 = (float*)(ws + 100 * MB);           // 1 MB
  ushortT* Xp0 = (ushortT*)(ws + 101 * MB);       // 0.5 MB packed
  ushortT* Xp1 = (ushortT*)(ws + 102 * MB);       // 0.5 MB

  k_normalize<<<NN, 256, 0, stream>>>(E, Enh, Enl);
  k_syrk_mfma<<<640, 256, 0, stream>>>(Enh, Enl, A);
  k_top7<<<NN / 4, 256, 0, stream>>>(A, sig);
  k_transform<<<NN, 256, 0, stream>>>(A, sig, parts);
  k_mean<<<1, 256, 0, stream>>>(parts, meanb);
  k_thresh_pack<<<8192, 256, 0, stream>>>(A, sig, meanb, ApL, ApU);
  k_xlabp<<<1024, 256, 0, stream>>>(labels, Xlabp);
  k_xinit<<<128, 64, 0, stream>>>(Xf0, Xp0);
  // Ylab = A[unlab, :2048] @ onehot  (fused kernel, store-raw mode)
  k_iterF<false><<<128, 512, 0, stream>>>(ApL, Xlabp, nullptr, nullptr, YlabF, nullptr);
  float* xf[2] = {Xf0, Xf1};
  ushortT* xp[2] = {Xp0, Xp1};
  int cur = 0;
  for (int it = 0; it < NITER; ++it) {
    int nxt = cur ^ 1;
    k_iterF<true><<<128, 512, 0, stream>>>(ApU, xp[cur], YlabF, xf[cur], xf[nxt], xp[nxt]);
    cur = nxt;
  }
  k_output<<<1600, 256, 0, stream>>>(xf[cur], labels, out);
}

// Round 10
// 511.014 us; speedup vs baseline: 1.3538x; 1.3538x over previous
//
#include <hip/hip_runtime.h>
#include <math.h>

typedef unsigned short ushortT;
typedef __attribute__((ext_vector_type(8))) short short8;
typedef __attribute__((ext_vector_type(4))) float f32x4;

#define NN 4096
#define DD 1024
#define NC 100
#define CP 128
#define NLAB 2048
#define NITER 30

__device__ __forceinline__ ushortT bf16rn(float x) {
  unsigned u = __float_as_uint(x);
  unsigned r = (u + 0x7fffu + ((u >> 16) & 1u)) >> 16;
  return (ushortT)r;
}
__device__ __forceinline__ float bf2f(ushortT h) {
  return __uint_as_float(((unsigned)h) << 16);
}
__device__ __forceinline__ void gload16(const void* g, void* l) {
  __builtin_amdgcn_global_load_lds((const __attribute__((address_space(1))) char*)g,
                                   (__attribute__((address_space(3))) char*)l, 16, 0, 0);
}

// ---------------- normalize rows -> bf16 hi/lo splits ----------------
__global__ __launch_bounds__(256) void k_normalize(const float* __restrict__ E,
                                                   ushortT* __restrict__ Enh,
                                                   ushortT* __restrict__ Enl) {
  int row = blockIdx.x, t = threadIdx.x;
  const float4* e4 = (const float4*)(E + (size_t)row * DD);
  float4 v = e4[t];
  float ss = v.x * v.x + v.y * v.y + v.z * v.z + v.w * v.w;
  __shared__ float red[4];
  int lane = t & 63, w = t >> 6;
#pragma unroll
  for (int off = 32; off; off >>= 1) ss += __shfl_xor(ss, off);
  if (lane == 0) red[w] = ss;
  __syncthreads();
  float tot = red[0] + red[1] + red[2] + red[3];
  float d = fmaxf(sqrtf(tot), 1e-12f);
  float xs[4] = {v.x / d, v.y / d, v.z / d, v.w / d};
  ushort4 hv, lv;
  ushortT h;
  h = bf16rn(xs[0]); hv.x = h; lv.x = bf16rn(xs[0] - bf2f(h));
  h = bf16rn(xs[1]); hv.y = h; lv.y = bf16rn(xs[1] - bf2f(h));
  h = bf16rn(xs[2]); hv.z = h; lv.z = bf16rn(xs[2] - bf2f(h));
  h = bf16rn(xs[3]); hv.w = h; lv.w = bf16rn(xs[3] - bf2f(h));
  ((ushort4*)Enh)[(size_t)row * 256 + t] = hv;
  ((ushort4*)Enl)[(size_t)row * 256 + t] = lv;
}

// ---------------- A0 = relu(En@En^T), 3-term bf16 split; diag=1 ----------------
// Upper-tri tiles, XCD-banded; SINGLE-buffered 36 KB LDS -> 4 blocks/CU.
__global__ __launch_bounds__(256, 4) void k_syrk_mfma(const ushortT* __restrict__ Enh,
                                                      const ushortT* __restrict__ Enl,
                                                      float* __restrict__ A) {
  int xg = (int)blockIdx.x & 7;
  int j = (int)blockIdx.x >> 3;  // 0..79
  int bi = -1, bj = 0;
#pragma unroll
  for (int p = 0; p < 4; ++p) {
    int bic = xg + (p << 3);
    int c = 32 - bic;
    if (bi < 0) {
      if (j < c) { bi = bic; bj = bic + j; } else j -= c;
    }
  }
  if (bi < 0) return;
  __shared__ ushortT lds[18432];  // A-tile @0, B-tile @8192; T overlay 34.8 KB
  int t = threadIdx.x;
  int l = t & 63, w = t >> 6;
  int i0 = bi << 7, j0 = bj << 7;
  int wr = w >> 1, wc = w & 1;
  f32x4 zz = {0.f, 0.f, 0.f, 0.f};
  f32x4 acc[4][4];
#pragma unroll
  for (int m = 0; m < 4; ++m)
#pragma unroll
    for (int n = 0; n < 4; ++n) acc[m][n] = zz;
  int arow_l = l & 15, kslot = l >> 4;

  for (int s = 0; s < 48; ++s) {
    int term = s >> 4;
    int kk0 = (s & 15) << 6;
    const ushortT* sa = (term == 2) ? Enl : Enh;
    const ushortT* sb = (term == 1) ? Enl : Enh;
#pragma unroll
    for (int q = 0; q < 4; ++q) {
      int n = (q << 8) + t;
      int r = n >> 3, p = n & 7;
      int col = (p ^ (r & 7)) << 3;
      gload16(sa + (size_t)(i0 + r) * DD + kk0 + col, &lds[n << 3]);
      gload16(sb + (size_t)(j0 + r) * DD + kk0 + col, &lds[8192 + (n << 3)]);
    }
    __syncthreads();
#pragma unroll
    for (int kk = 0; kk < 2; ++kk) {
      int g = (kk << 2) + kslot;
      short8 av[4], bv[4];
#pragma unroll
      for (int m = 0; m < 4; ++m) {
        int r = (wr << 6) + (m << 4) + arow_l;
        av[m] = *(const short8*)&lds[(r << 6) + ((g ^ (r & 7)) << 3)];
      }
#pragma unroll
      for (int n = 0; n < 4; ++n) {
        int r = (wc << 6) + (n << 4) + arow_l;
        bv[n] = *(const short8*)&lds[8192 + (r << 6) + ((g ^ (r & 7)) << 3)];
      }
#pragma unroll
      for (int m = 0; m < 4; ++m)
#pragma unroll
        for (int n = 0; n < 4; ++n)
          acc[m][n] = __builtin_amdgcn_mfma_f32_16x16x32_bf16(av[m], bv[n], acc[m][n], 0, 0, 0);
    }
    __syncthreads();
  }
  int rbase = (l >> 4) << 2;
#pragma unroll
  for (int m = 0; m < 4; ++m) {
#pragma unroll
    for (int n = 0; n < 4; ++n) {
#pragma unroll
      for (int r = 0; r < 4; ++r) {
        int gi = i0 + (wr << 6) + (m << 4) + rbase + r;
        int gj = j0 + (wc << 6) + (n << 4) + (l & 15);
        float v = fmaxf(acc[m][n][r], 0.0f);
        if (gi == gj) v = 1.0f;
        A[(size_t)gi * NN + gj] = v;
      }
    }
  }
  if (bi != bj) {
    float* T = (float*)&lds[0];
#pragma unroll
    for (int c2 = 0; c2 < 2; ++c2) {
      __syncthreads();
      if (wr == c2) {
#pragma unroll
        for (int m = 0; m < 4; ++m)
#pragma unroll
          for (int n = 0; n < 4; ++n)
#pragma unroll
            for (int r = 0; r < 4; ++r)
              T[(((wc << 6) + (n << 4) + (l & 15)) * 68) + (m << 4) + rbase + r] =
                  fmaxf(acc[m][n][r], 0.0f);
      }
      __syncthreads();
      int lj = t >> 1, cg = (t & 1) << 5;
#pragma unroll
      for (int q = 0; q < 8; ++q) {
        float4 vq = *(const float4*)&T[lj * 68 + cg + (q << 2)];
        *(float4*)&A[(size_t)(j0 + lj) * NN + i0 + (c2 << 6) + cg + (q << 2)] = vq;
      }
    }
  }
}

// ---------------- sigma[i] = 7th largest of row i ----------------
__device__ __forceinline__ void ins7(float (&tv)[7], float v) {
  if (v > tv[6]) {
#pragma unroll
    for (int s = 0; s < 7; s++) {
      if (v > tv[s]) { float tmp = tv[s]; tv[s] = v; v = tmp; }
    }
  }
}
__global__ __launch_bounds__(256) void k_top7(const float* __restrict__ A,
                                              float* __restrict__ sig) {
  int w = threadIdx.x >> 6, lane = threadIdx.x & 63;
  int row = (blockIdx.x << 2) + w;
  const float4* a4 = (const float4*)(A + (size_t)row * NN);
  float tv[7];
#pragma unroll
  for (int i = 0; i < 7; i++) tv[i] = -1.0f;
  for (int k = 0; k < 16; k++) {
    float4 v = a4[(k << 6) + lane];
    ins7(tv, v.x); ins7(tv, v.y); ins7(tv, v.z); ins7(tv, v.w);
  }
  int head = 0;
  float seventh = 0.0f;
  for (int r = 0; r < 7; r++) {
    float h = (head < 7) ? tv[head] : -1.0f;
    float m = h;
#pragma unroll
    for (int off = 32; off; off >>= 1) m = fmaxf(m, __shfl_xor(m, off));
    unsigned long long ball = __ballot(h == m);
    if (lane == (__ffsll(ball) - 1)) head++;
    seventh = m;
  }
  if (lane == 0) sig[row] = seventh;
}

// ---------------- mean pass: sum exp(-(A^2)/(si*sj)) per row, no store ----------------
__global__ __launch_bounds__(256) void k_transform(const float* __restrict__ A,
                                                   const float* __restrict__ sig,
                                                   double* __restrict__ parts) {
  int row = blockIdx.x;
  float si = sig[row];
  const float4* a4 = (const float4*)(A + (size_t)row * NN);
  const float4* s4 = (const float4*)sig;
  int t = threadIdx.x;
  double local = 0.0;
#pragma unroll
  for (int k = 0; k < 4; k++) {
    int j = (k << 8) + t;
    float4 v = a4[j];
    float4 sg = s4[j];
    local += (double)expf(-(v.x * v.x) / (si * sg.x)) +
             (double)expf(-(v.y * v.y) / (si * sg.y)) +
             (double)expf(-(v.z * v.z) / (si * sg.z)) +
             (double)expf(-(v.w * v.w) / (si * sg.w));
  }
  __shared__ double dred[4];
  int lane = t & 63, wv = t >> 6;
#pragma unroll
  for (int off = 32; off; off >>= 1) local += __shfl_xor(local, off);
  if (lane == 0) dred[wv] = local;
  __syncthreads();
  if (t == 0) parts[row] = dred[0] + dred[1] + dred[2] + dred[3];
}

__global__ __launch_bounds__(256) void k_mean(const double* __restrict__ parts,
                                              float* __restrict__ meanb) {
  int t = threadIdx.x;
  double local = 0.0;
#pragma unroll
  for (int k = 0; k < NN / 256; k++) local += parts[(k << 8) + t];
  __shared__ double dred[4];
  int lane = t & 63, wv = t >> 6;
#pragma unroll
  for (int off = 32; off; off >>= 1) local += __shfl_xor(local, off);
  if (lane == 0) dred[wv] = local;
  __syncthreads();
  if (t == 0) meanb[0] = (float)((dred[0] + dred[1] + dred[2] + dred[3]) / ((double)NN * (double)NN));
}

// ---------------- thresh: recompute exp on bottom half, threshold, pack ----------------
__global__ __launch_bounds__(256) void k_thresh_pack(const float* __restrict__ A,
                                                     const float* __restrict__ sig,
                                                     const float* __restrict__ meanb,
                                                     ushortT* __restrict__ ApL,
                                                     ushortT* __restrict__ ApU) {
  float m = meanb[0];
  int i4 = ((int)blockIdx.x << 8) + threadIdx.x;  // 2M over [2048][1024]
  int row2 = i4 >> 10;
  int col4 = (i4 & 1023) << 2;
  int grow = NLAB + row2;
  float si = sig[grow];
  float4 v = *(const float4*)&A[(size_t)grow * NN + col4];
  float4 sg = *(const float4*)&sig[col4];
  float c0 = expf(-(v.x * v.x) / (si * sg.x));
  float c1 = expf(-(v.y * v.y) / (si * sg.y));
  float c2 = expf(-(v.z * v.z) / (si * sg.z));
  float c3 = expf(-(v.w * v.w) / (si * sg.w));
  c0 = (c0 < m) ? 0.0f : c0;
  c1 = (c1 < m) ? 0.0f : c1;
  c2 = (c2 < m) ? 0.0f : c2;
  c3 = (c3 < m) ? 0.0f : c3;
  int half = col4 >> 11;
  int cc = col4 & 2047;
  int rt = row2 >> 4, arow = row2 & 15;
  int kc = cc >> 5, khi = (cc >> 3) & 3, k0 = cc & 7;
  ushortT* dst = half ? ApU : ApL;
  ushort4 hv;
  hv.x = bf16rn(c0); hv.y = bf16rn(c1); hv.z = bf16rn(c2); hv.w = bf16rn(c3);
  *(ushort4*)&dst[((size_t)((rt << 6) + kc) << 9) + (khi << 7) + (arow << 3) + k0] = hv;
}

// ---------------- one-hot labels, packed layout ----------------
__global__ __launch_bounds__(256) void k_xlabp(const int* __restrict__ labels,
                                               ushortT* __restrict__ Xlabp) {
  int idx = ((int)blockIdx.x << 8) + threadIdx.x;  // 262144
  int c = idx >> 11, j = idx & 2047;
  int kc = j >> 5, khi = (j >> 3) & 3, k0 = j & 7;
  int cf = c >> 4, slot = c & 15;
  Xlabp[((size_t)(((kc << 3) + cf) << 2) + khi) * 128 + (slot << 3) + k0] =
      (labels[j] == c) ? (ushortT)0x3F80 : (ushortT)0;
}

// ---------------- X init ----------------
__global__ __launch_bounds__(64) void k_xinit(float* __restrict__ Xf,
                                              ushortT* __restrict__ Xp) {
  int rt = blockIdx.x, l = threadIdx.x;
  int col = l & 15, rg4 = l >> 4;
  int kc = rt >> 1;
  int kk = ((rt & 1) << 4) + (rg4 << 2);
  int khi = kk >> 3, k0 = kk & 7;
#pragma unroll
  for (int cf = 0; cf < 8; ++cf) {
    int cls = (cf << 4) + col;
    float v = (cls < NC) ? 0.01f : 0.0f;
    ((f32x4*)Xf)[(size_t)((rt << 3) + cf) * 64 + l] = (f32x4){v, v, v, v};
    ushortT h = bf16rn(v);
    ushort4 hv = {h, h, h, h};
    *(ushort4*)&Xp[((size_t)(((kc << 3) + cf) << 2) + khi) * 128 + (col << 3) + k0] = hv;
  }
}

// ---------------- P: partial GEMM, 4 K-slices of 512, f32 partials ----------------
// 512 blocks = 128 rt x 4 s (rt XCD-pinned); 4 waves; wave = rt x K=128 x 128 cols.
// LDS cross-wave reduce -> one f32x4 slice store per (s,rt,cf).
__global__ __launch_bounds__(256) void k_gP(const ushortT* __restrict__ Ap,
                                            const ushortT* __restrict__ Xp,
                                            float* __restrict__ Pp) {
  int t = threadIdx.x, l = t & 63, w = t >> 6;
  int bid = (int)blockIdx.x;
  int rt = ((bid & 7) << 4) + ((bid >> 3) & 15);
  int s = bid >> 7;  // 0..3
  int kc0 = (s << 4) + (w << 2);
  const ushortT* ab = Ap + ((size_t)rt << 15) + ((size_t)kc0 << 9) + (l << 3);
  const ushortT* xb = Xp + ((size_t)kc0 << 12) + (l << 3);
  short8 av[4];
#pragma unroll
  for (int i = 0; i < 4; ++i) av[i] = *(const short8*)(ab + ((size_t)i << 9));
  f32x4 acc[8];
#pragma unroll
  for (int cf = 0; cf < 8; ++cf) {
    acc[cf] = (f32x4){0.f, 0.f, 0.f, 0.f};
#pragma unroll
    for (int i = 0; i < 4; ++i) {
      short8 bv = *(const short8*)(xb + ((size_t)i << 12) + (cf << 9));
      acc[cf] = __builtin_amdgcn_mfma_f32_16x16x32_bf16(av[i], bv, acc[cf], 0, 0, 0);
    }
  }
  __shared__ float red[4][8][64][4];  // 32 KB
#pragma unroll
  for (int cf = 0; cf < 8; ++cf) *(f32x4*)&red[w][cf][l][0] = acc[cf];
  __syncthreads();
  if (w < 2) {
#pragma unroll
    for (int q = 0; q < 4; ++q) {
      int cf = (w << 2) + q;
      f32x4 sum = *(const f32x4*)&red[0][cf][l][0];
#pragma unroll
      for (int wp = 1; wp < 4; ++wp) {
        f32x4 p = *(const f32x4*)&red[wp][cf][l][0];
        sum[0] += p[0]; sum[1] += p[1]; sum[2] += p[2]; sum[3] += p[3];
      }
      ((f32x4*)Pp)[((size_t)(((s << 7) + rt) << 3) + cf) * 64 + l] = sum;
    }
  }
}

// ---------------- U: reduce 4 f32 partial slices + fused update ----------------
template <bool UPDATE>
__global__ __launch_bounds__(64) void k_updU(const float* __restrict__ Pp,
                                             const float* __restrict__ YlabF,
                                             const float* __restrict__ XfPrev,
                                             float* __restrict__ XfOut,
                                             ushortT* __restrict__ XpOut) {
  int rt = blockIdx.x, l = threadIdx.x;
  f32x4 acc[8];
#pragma unroll
  for (int cf = 0; cf < 8; ++cf) acc[cf] = (f32x4){0.f, 0.f, 0.f, 0.f};
  const f32x4* pq = (const f32x4*)Pp;
#pragma unroll
  for (int s = 0; s < 4; ++s) {
#pragma unroll
    for (int cf = 0; cf < 8; ++cf) {
      f32x4 p = pq[((size_t)(((s << 7) + rt) << 3) + cf) * 64 + l];
      acc[cf][0] += p[0]; acc[cf][1] += p[1];
      acc[cf][2] += p[2]; acc[cf][3] += p[3];
    }
  }
  if constexpr (!UPDATE) {
#pragma unroll
    for (int cf = 0; cf < 8; ++cf)
      ((f32x4*)XfOut)[(size_t)((rt << 3) + cf) * 64 + l] = acc[cf];
  } else {
    f32x4 mult[8];
    f32x4 rs = {0.f, 0.f, 0.f, 0.f};
#pragma unroll
    for (int cf = 0; cf < 8; ++cf) {
      f32x4 yl = ((const f32x4*)YlabF)[(size_t)((rt << 3) + cf) * 64 + l];
      f32x4 xv = ((const f32x4*)XfPrev)[(size_t)((rt << 3) + cf) * 64 + l];
#pragma unroll
      for (int r = 0; r < 4; ++r) {
        mult[cf][r] = fmaf(xv[r], acc[cf][r] + yl[r], xv[r]);
        rs[r] += mult[cf][r];
      }
    }
#pragma unroll
    for (int msk = 1; msk < 16; msk <<= 1) {
#pragma unroll
      for (int r = 0; r < 4; ++r) rs[r] += __shfl_xor(rs[r], msk);
    }
    f32x4 dn;
#pragma unroll
    for (int r = 0; r < 4; ++r) dn[r] = rs[r] + 1e-8f;
    int col = l & 15, rg4 = l >> 4;
    int kc = rt >> 1;
    int kk = ((rt & 1) << 4) + (rg4 << 2);
    int khi = kk >> 3, k0 = kk & 7;
#pragma unroll
    for (int cf = 0; cf < 8; ++cf) {
      f32x4 ov;
#pragma unroll
      for (int r = 0; r < 4; ++r) ov[r] = mult[cf][r] / dn[r];
      ((f32x4*)XfOut)[(size_t)((rt << 3) + cf) * 64 + l] = ov;
      ushort4 xo;
      xo.x = bf16rn(ov[0]); xo.y = bf16rn(ov[1]);
      xo.z = bf16rn(ov[2]); xo.w = bf16rn(ov[3]);
      *(ushort4*)&XpOut[((size_t)(((kc << 3) + cf) << 2) + khi) * 128 + (col << 3) + k0] = xo;
    }
  }
}

// ---------------- output assembly ----------------
__global__ __launch_bounds__(256) void k_output(const float* __restrict__ Xf,
                                                const int* __restrict__ labels,
                                                float* __restrict__ out) {
  int idx = ((int)blockIdx.x << 8) + threadIdx.x;  // 409600
  int i = idx / NC, c = idx - i * NC;
  float v;
  if (i < NLAB) {
    v = (labels[i] == c) ? 1.0f : 0.0f;
  } else {
    int row = i - NLAB;
    int rt = row >> 4, r = row & 15;
    int rg4 = r >> 2, reg = r & 3;
    int cf = c >> 4, col = c & 15;
    v = Xf[((size_t)(((rt << 3) + cf) << 6) + (rg4 << 4) + col) * 4 + reg];
  }
  out[idx] = v;
}

extern "C" void kernel_launch(void* const* d_in, const int* in_sizes, int n_in,
                              void* d_out, int out_size, void* d_ws, size_t ws_size,
                              hipStream_t stream) {
  const float* E = (const float*)d_in[0];
  const int* labels = (const int*)d_in[1];
  float* out = (float*)d_out;
  char* ws = (char*)d_ws;
  const size_t MB = 1024 * 1024;

  float* A = (float*)ws;                          // 64 MB
  ushortT* Enh = (ushortT*)(ws + 64 * MB);        // 8 MB
  ushortT* Enl = (ushortT*)(ws + 72 * MB);        // 8 MB
  ushortT* ApL = (ushortT*)(ws + 80 * MB);        // 8 MB packed A[:, :2048]
  ushortT* ApU = (ushortT*)(ws + 88 * MB);        // 8 MB packed A[:, 2048:]
  float* sig = (float*)(ws + 96 * MB);
  double* parts = (double*)(ws + 96 * MB + 65536);
  float* meanb = (float*)(ws + 96 * MB + 131072);
  ushortT* Xlabp = (ushortT*)(ws + 97 * MB);      // 0.5 MB packed
  float* YlabF = (float*)(ws + 98 * MB);          // 1 MB frag-major
  float* Xf0 = (float*)(ws + 99 * MB);            // 1 MB frag-major
  float* Xf1 = (float*)(ws + 100 * MB);           // 1 MB
  ushortT* Xp0 = (ushortT*)(ws + 101 * MB);       // 0.5 MB packed
  ushortT* Xp1 = (ushortT*)(ws + 102 * MB);       // 0.5 MB
  float* Pp = (float*)(ws + 104 * MB);            // 4 MB f32 partials

  k_normalize<<<NN, 256, 0, stream>>>(E, Enh, Enl);
  k_syrk_mfma<<<640, 256, 0, stream>>>(Enh, Enl, A);
  k_top7<<<NN / 4, 256, 0, stream>>>(A, sig);
  k_transform<<<NN, 256, 0, stream>>>(A, sig, parts);
  k_mean<<<1, 256, 0, stream>>>(parts, meanb);
  k_thresh_pack<<<8192, 256, 0, stream>>>(A, sig, meanb, ApL, ApU);
  k_xlabp<<<1024, 256, 0, stream>>>(labels, Xlabp);
  k_xinit<<<128, 64, 0, stream>>>(Xf0, Xp0);
  k_gP<<<512, 256, 0, stream>>>(ApL, Xlabp, Pp);
  k_updU<false><<<128, 64, 0, stream>>>(Pp, nullptr, nullptr, YlabF, nullptr);
  float* xf[2] = {Xf0, Xf1};
  ushortT* xp[2] = {Xp0, Xp1};
  int cur = 0;
  for (int it = 0; it < NITER; ++it) {
    int nxt = cur ^ 1;
    k_gP<<<512, 256, 0, stream>>>(ApU, xp[cur], Pp);
    k_updU<true><<<128, 64, 0, stream>>>(Pp, YlabF, xf[cur], xf[nxt], xp[nxt]);
    cur = nxt;
  }
  k_output<<<1600, 256, 0, stream>>>(xf[cur], labels, out);
}

// Round 11
// 478.441 us; speedup vs baseline: 1.4459x; 1.0681x over previous
//
#include <hip/hip_runtime.h>
#include <math.h>

typedef unsigned short ushortT;
typedef __attribute__((ext_vector_type(8))) short short8;
typedef __attribute__((ext_vector_type(4))) float f32x4;

#define NN 4096
#define DD 1024
#define NC 100
#define CP 128
#define NLAB 2048
#define NITER 30

__device__ __forceinline__ ushortT bf16rn(float x) {
  unsigned u = __float_as_uint(x);
  unsigned r = (u + 0x7fffu + ((u >> 16) & 1u)) >> 16;
  return (ushortT)r;
}
__device__ __forceinline__ float bf2f(ushortT h) {
  return __uint_as_float(((unsigned)h) << 16);
}
__device__ __forceinline__ void gload16(const void* g, void* l) {
  __builtin_amdgcn_global_load_lds((const __attribute__((address_space(1))) char*)g,
                                   (__attribute__((address_space(3))) char*)l, 16, 0, 0);
}

// ---------------- normalize rows -> bf16 hi/lo splits ----------------
__global__ __launch_bounds__(256) void k_normalize(const float* __restrict__ E,
                                                   ushortT* __restrict__ Enh,
                                                   ushortT* __restrict__ Enl) {
  int row = blockIdx.x, t = threadIdx.x;
  const float4* e4 = (const float4*)(E + (size_t)row * DD);
  float4 v = e4[t];
  float ss = v.x * v.x + v.y * v.y + v.z * v.z + v.w * v.w;
  __shared__ float red[4];
  int lane = t & 63, w = t >> 6;
#pragma unroll
  for (int off = 32; off; off >>= 1) ss += __shfl_xor(ss, off);
  if (lane == 0) red[w] = ss;
  __syncthreads();
  float tot = red[0] + red[1] + red[2] + red[3];
  float d = fmaxf(sqrtf(tot), 1e-12f);
  float xs[4] = {v.x / d, v.y / d, v.z / d, v.w / d};
  ushort4 hv, lv;
  ushortT h;
  h = bf16rn(xs[0]); hv.x = h; lv.x = bf16rn(xs[0] - bf2f(h));
  h = bf16rn(xs[1]); hv.y = h; lv.y = bf16rn(xs[1] - bf2f(h));
  h = bf16rn(xs[2]); hv.z = h; lv.z = bf16rn(xs[2] - bf2f(h));
  h = bf16rn(xs[3]); hv.w = h; lv.w = bf16rn(xs[3] - bf2f(h));
  ((ushort4*)Enh)[(size_t)row * 256 + t] = hv;
  ((ushort4*)Enl)[(size_t)row * 256 + t] = lv;
}

// ---------------- A0 = relu(En@En^T), 3-term bf16 split; diag=1 ----------------
// Upper-tri tiles, XCD-banded; single-buffered 36 KB LDS -> 4 blocks/CU.
__global__ __launch_bounds__(256, 4) void k_syrk_mfma(const ushortT* __restrict__ Enh,
                                                      const ushortT* __restrict__ Enl,
                                                      float* __restrict__ A) {
  int xg = (int)blockIdx.x & 7;
  int j = (int)blockIdx.x >> 3;  // 0..79
  int bi = -1, bj = 0;
#pragma unroll
  for (int p = 0; p < 4; ++p) {
    int bic = xg + (p << 3);
    int c = 32 - bic;
    if (bi < 0) {
      if (j < c) { bi = bic; bj = bic + j; } else j -= c;
    }
  }
  if (bi < 0) return;
  __shared__ ushortT lds[18432];  // A-tile @0, B-tile @8192; T overlay 34.8 KB
  int t = threadIdx.x;
  int l = t & 63, w = t >> 6;
  int i0 = bi << 7, j0 = bj << 7;
  int wr = w >> 1, wc = w & 1;
  f32x4 zz = {0.f, 0.f, 0.f, 0.f};
  f32x4 acc[4][4];
#pragma unroll
  for (int m = 0; m < 4; ++m)
#pragma unroll
    for (int n = 0; n < 4; ++n) acc[m][n] = zz;
  int arow_l = l & 15, kslot = l >> 4;

  for (int s = 0; s < 48; ++s) {
    int term = s >> 4;
    int kk0 = (s & 15) << 6;
    const ushortT* sa = (term == 2) ? Enl : Enh;
    const ushortT* sb = (term == 1) ? Enl : Enh;
#pragma unroll
    for (int q = 0; q < 4; ++q) {
      int n = (q << 8) + t;
      int r = n >> 3, p = n & 7;
      int col = (p ^ (r & 7)) << 3;
      gload16(sa + (size_t)(i0 + r) * DD + kk0 + col, &lds[n << 3]);
      gload16(sb + (size_t)(j0 + r) * DD + kk0 + col, &lds[8192 + (n << 3)]);
    }
    __syncthreads();
#pragma unroll
    for (int kk = 0; kk < 2; ++kk) {
      int g = (kk << 2) + kslot;
      short8 av[4], bv[4];
#pragma unroll
      for (int m = 0; m < 4; ++m) {
        int r = (wr << 6) + (m << 4) + arow_l;
        av[m] = *(const short8*)&lds[(r << 6) + ((g ^ (r & 7)) << 3)];
      }
#pragma unroll
      for (int n = 0; n < 4; ++n) {
        int r = (wc << 6) + (n << 4) + arow_l;
        bv[n] = *(const short8*)&lds[8192 + (r << 6) + ((g ^ (r & 7)) << 3)];
      }
#pragma unroll
      for (int m = 0; m < 4; ++m)
#pragma unroll
        for (int n = 0; n < 4; ++n)
          acc[m][n] = __builtin_amdgcn_mfma_f32_16x16x32_bf16(av[m], bv[n], acc[m][n], 0, 0, 0);
    }
    __syncthreads();
  }
  int rbase = (l >> 4) << 2;
#pragma unroll
  for (int m = 0; m < 4; ++m) {
#pragma unroll
    for (int n = 0; n < 4; ++n) {
#pragma unroll
      for (int r = 0; r < 4; ++r) {
        int gi = i0 + (wr << 6) + (m << 4) + rbase + r;
        int gj = j0 + (wc << 6) + (n << 4) + (l & 15);
        float v = fmaxf(acc[m][n][r], 0.0f);
        if (gi == gj) v = 1.0f;
        A[(size_t)gi * NN + gj] = v;
      }
    }
  }
  if (bi != bj) {
    float* T = (float*)&lds[0];
#pragma unroll
    for (int c2 = 0; c2 < 2; ++c2) {
      __syncthreads();
      if (wr == c2) {
#pragma unroll
        for (int m = 0; m < 4; ++m)
#pragma unroll
          for (int n = 0; n < 4; ++n)
#pragma unroll
            for (int r = 0; r < 4; ++r)
              T[(((wc << 6) + (n << 4) + (l & 15)) * 68) + (m << 4) + rbase + r] =
                  fmaxf(acc[m][n][r], 0.0f);
      }
      __syncthreads();
      int lj = t >> 1, cg = (t & 1) << 5;
#pragma unroll
      for (int q = 0; q < 8; ++q) {
        float4 vq = *(const float4*)&T[lj * 68 + cg + (q << 2)];
        *(float4*)&A[(size_t)(j0 + lj) * NN + i0 + (c2 << 6) + cg + (q << 2)] = vq;
      }
    }
  }
}

// ---------------- sigma[i] = 7th largest of row i ----------------
__device__ __forceinline__ void ins7(float (&tv)[7], float v) {
  if (v > tv[6]) {
#pragma unroll
    for (int s = 0; s < 7; s++) {
      if (v > tv[s]) { float tmp = tv[s]; tv[s] = v; v = tmp; }
    }
  }
}
__global__ __launch_bounds__(256) void k_top7(const float* __restrict__ A,
                                              float* __restrict__ sig) {
  int w = threadIdx.x >> 6, lane = threadIdx.x & 63;
  int row = (blockIdx.x << 2) + w;
  const float4* a4 = (const float4*)(A + (size_t)row * NN);
  float tv[7];
#pragma unroll
  for (int i = 0; i < 7; i++) tv[i] = -1.0f;
  for (int k = 0; k < 16; k++) {
    float4 v = a4[(k << 6) + lane];
    ins7(tv, v.x); ins7(tv, v.y); ins7(tv, v.z); ins7(tv, v.w);
  }
  int head = 0;
  float seventh = 0.0f;
  for (int r = 0; r < 7; r++) {
    float h = (head < 7) ? tv[head] : -1.0f;
    float m = h;
#pragma unroll
    for (int off = 32; off; off >>= 1) m = fmaxf(m, __shfl_xor(m, off));
    unsigned long long ball = __ballot(h == m);
    if (lane == (__ffsll(ball) - 1)) head++;
    seventh = m;
  }
  if (lane == 0) sig[row] = seventh;
}

// ---------------- mean pass: sum exp(-(A^2)/(si*sj)) per row, no store ----------------
__global__ __launch_bounds__(256) void k_transform(const float* __restrict__ A,
                                                   const float* __restrict__ sig,
                                                   double* __restrict__ parts) {
  int row = blockIdx.x;
  float si = sig[row];
  const float4* a4 = (const float4*)(A + (size_t)row * NN);
  const float4* s4 = (const float4*)sig;
  int t = threadIdx.x;
  double local = 0.0;
#pragma unroll
  for (int k = 0; k < 4; k++) {
    int j = (k << 8) + t;
    float4 v = a4[j];
    float4 sg = s4[j];
    local += (double)expf(-(v.x * v.x) / (si * sg.x)) +
             (double)expf(-(v.y * v.y) / (si * sg.y)) +
             (double)expf(-(v.z * v.z) / (si * sg.z)) +
             (double)expf(-(v.w * v.w) / (si * sg.w));
  }
  __shared__ double dred[4];
  int lane = t & 63, wv = t >> 6;
#pragma unroll
  for (int off = 32; off; off >>= 1) local += __shfl_xor(local, off);
  if (lane == 0) dred[wv] = local;
  __syncthreads();
  if (t == 0) parts[row] = dred[0] + dred[1] + dred[2] + dred[3];
}

__global__ __launch_bounds__(256) void k_mean(const double* __restrict__ parts,
                                              float* __restrict__ meanb) {
  int t = threadIdx.x;
  double local = 0.0;
#pragma unroll
  for (int k = 0; k < NN / 256; k++) local += parts[(k << 8) + t];
  __shared__ double dred[4];
  int lane = t & 63, wv = t >> 6;
#pragma unroll
  for (int off = 32; off; off >>= 1) local += __shfl_xor(local, off);
  if (lane == 0) dred[wv] = local;
  __syncthreads();
  if (t == 0) meanb[0] = (float)((dred[0] + dred[1] + dred[2] + dred[3]) / ((double)NN * (double)NN));
}

// ---------------- thresh: recompute exp on bottom half, threshold, pack ----------------
__global__ __launch_bounds__(256) void k_thresh_pack(const float* __restrict__ A,
                                                     const float* __restrict__ sig,
                                                     const float* __restrict__ meanb,
                                                     ushortT* __restrict__ ApL,
                                                     ushortT* __restrict__ ApU) {
  float m = meanb[0];
  int i4 = ((int)blockIdx.x << 8) + threadIdx.x;  // 2M over [2048][1024]
  int row2 = i4 >> 10;
  int col4 = (i4 & 1023) << 2;
  int grow = NLAB + row2;
  float si = sig[grow];
  float4 v = *(const float4*)&A[(size_t)grow * NN + col4];
  float4 sg = *(const float4*)&sig[col4];
  float c0 = expf(-(v.x * v.x) / (si * sg.x));
  float c1 = expf(-(v.y * v.y) / (si * sg.y));
  float c2 = expf(-(v.z * v.z) / (si * sg.z));
  float c3 = expf(-(v.w * v.w) / (si * sg.w));
  c0 = (c0 < m) ? 0.0f : c0;
  c1 = (c1 < m) ? 0.0f : c1;
  c2 = (c2 < m) ? 0.0f : c2;
  c3 = (c3 < m) ? 0.0f : c3;
  int half = col4 >> 11;
  int cc = col4 & 2047;
  int rt = row2 >> 4, arow = row2 & 15;
  int kc = cc >> 5, khi = (cc >> 3) & 3, k0 = cc & 7;
  ushortT* dst = half ? ApU : ApL;
  ushort4 hv;
  hv.x = bf16rn(c0); hv.y = bf16rn(c1); hv.z = bf16rn(c2); hv.w = bf16rn(c3);
  *(ushort4*)&dst[((size_t)((rt << 6) + kc) << 9) + (khi << 7) + (arow << 3) + k0] = hv;
}

// ---------------- one-hot labels, packed layout ----------------
__global__ __launch_bounds__(256) void k_xlabp(const int* __restrict__ labels,
                                               ushortT* __restrict__ Xlabp) {
  int idx = ((int)blockIdx.x << 8) + threadIdx.x;  // 262144
  int c = idx >> 11, j = idx & 2047;
  int kc = j >> 5, khi = (j >> 3) & 3, k0 = j & 7;
  int cf = c >> 4, slot = c & 15;
  Xlabp[((size_t)(((kc << 3) + cf) << 2) + khi) * 128 + (slot << 3) + k0] =
      (labels[j] == c) ? (ushortT)0x3F80 : (ushortT)0;
}

// ---------------- X init ----------------
__global__ __launch_bounds__(64) void k_xinit(float* __restrict__ Xf,
                                              ushortT* __restrict__ Xp) {
  int rt = blockIdx.x, l = threadIdx.x;
  int col = l & 15, rg4 = l >> 4;
  int kc = rt >> 1;
  int kk = ((rt & 1) << 4) + (rg4 << 2);
  int khi = kk >> 3, k0 = kk & 7;
#pragma unroll
  for (int cf = 0; cf < 8; ++cf) {
    int cls = (cf << 4) + col;
    float v = (cls < NC) ? 0.01f : 0.0f;
    ((f32x4*)Xf)[(size_t)((rt << 3) + cf) * 64 + l] = (f32x4){v, v, v, v};
    ushortT h = bf16rn(v);
    ushort4 hv = {h, h, h, h};
    *(ushort4*)&Xp[((size_t)(((kc << 3) + cf) << 2) + khi) * 128 + (col << 3) + k0] = hv;
  }
}

// ---------------- Ylab path: partial GEMM + reduce (one-time) ----------------
__global__ __launch_bounds__(256) void k_gP(const ushortT* __restrict__ Ap,
                                            const ushortT* __restrict__ Xp,
                                            float* __restrict__ Pp) {
  int t = threadIdx.x, l = t & 63, w = t >> 6;
  int bid = (int)blockIdx.x;
  int rt = ((bid & 7) << 4) + ((bid >> 3) & 15);
  int s = bid >> 7;  // 0..3
  int kc0 = (s << 4) + (w << 2);
  const ushortT* ab = Ap + ((size_t)rt << 15) + ((size_t)kc0 << 9) + (l << 3);
  const ushortT* xb = Xp + ((size_t)kc0 << 12) + (l << 3);
  short8 av[4];
#pragma unroll
  for (int i = 0; i < 4; ++i) av[i] = *(const short8*)(ab + ((size_t)i << 9));
  f32x4 acc[8];
#pragma unroll
  for (int cf = 0; cf < 8; ++cf) {
    acc[cf] = (f32x4){0.f, 0.f, 0.f, 0.f};
#pragma unroll
    for (int i = 0; i < 4; ++i) {
      short8 bv = *(const short8*)(xb + ((size_t)i << 12) + (cf << 9));
      acc[cf] = __builtin_amdgcn_mfma_f32_16x16x32_bf16(av[i], bv, acc[cf], 0, 0, 0);
    }
  }
  __shared__ float red[4][8][64][4];  // 32 KB
#pragma unroll
  for (int cf = 0; cf < 8; ++cf) *(f32x4*)&red[w][cf][l][0] = acc[cf];
  __syncthreads();
  if (w < 2) {
#pragma unroll
    for (int q = 0; q < 4; ++q) {
      int cf = (w << 2) + q;
      f32x4 sum = *(const f32x4*)&red[0][cf][l][0];
#pragma unroll
      for (int wp = 1; wp < 4; ++wp) {
        f32x4 p = *(const f32x4*)&red[wp][cf][l][0];
        sum[0] += p[0]; sum[1] += p[1]; sum[2] += p[2]; sum[3] += p[3];
      }
      ((f32x4*)Pp)[((size_t)(((s << 7) + rt) << 3) + cf) * 64 + l] = sum;
    }
  }
}

__global__ __launch_bounds__(64) void k_updY(const float* __restrict__ Pp,
                                             float* __restrict__ YlabF) {
  int rt = blockIdx.x, l = threadIdx.x;
#pragma unroll
  for (int cf = 0; cf < 8; ++cf) {
    f32x4 acc = (f32x4){0.f, 0.f, 0.f, 0.f};
#pragma unroll
    for (int s = 0; s < 4; ++s) {
      f32x4 p = ((const f32x4*)Pp)[((size_t)(((s << 7) + rt) << 3) + cf) * 64 + l];
      acc[0] += p[0]; acc[1] += p[1]; acc[2] += p[2]; acc[3] += p[3];
    }
    ((f32x4*)YlabF)[(size_t)((rt << 3) + cf) * 64 + l] = acc;
  }
}

// ---------------- fused iteration, ONE launch: 256 blocks = 128 rt x 2 cf-halves ---
// Block: rt (16 rows) x half (4 cf) x full K=2048. Wave w: kc slice [w*16, w*16+16).
// Cross-block rowsum via device atomics (iteration-indexed buffers, 2 adds = exact).
__global__ __launch_bounds__(256) void k_it2(
    const ushortT* __restrict__ Ap,   // ApU packed [128 rt][64 kc][512]
    const ushortT* __restrict__ Xp,   // packed [64 kc][8 cf][512]
    const float* __restrict__ YlabF, const float* __restrict__ XfPrev,
    float* __restrict__ XfOut, ushortT* __restrict__ XpOut,
    float* __restrict__ sums2,        // [128][16] this iteration, zeroed
    int* __restrict__ cnt2) {         // [128] this iteration, zeroed
  __shared__ float red[4][4][64][4];  // [wave][cc][lane][reg] 16 KB
  __shared__ float sums_l[4][16];
  __shared__ float totl[16];
  int t = threadIdx.x, l = t & 63, w = t >> 6;
  int bid = (int)blockIdx.x;
  int rt = ((bid & 7) << 4) + ((bid >> 3) & 15);  // XCD-pinned rows
  int half = bid >> 7;                            // pair partner = bid ^ 128 (same XCD)
  int cf = (half << 2) + w;

  const ushortT* ab = Ap + ((size_t)rt << 15) + ((size_t)(w << 4) << 9) + (l << 3);
  const ushortT* xb = Xp + ((size_t)(w << 4) << 12) + ((size_t)(half << 2) << 9) + (l << 3);
  f32x4 acc[4];
#pragma unroll
  for (int cc = 0; cc < 4; ++cc) acc[cc] = (f32x4){0.f, 0.f, 0.f, 0.f};
#pragma unroll
  for (int i = 0; i < 16; ++i) {
    short8 av = *(const short8*)(ab + ((size_t)i << 9));
#pragma unroll
    for (int cc = 0; cc < 4; ++cc) {
      short8 bv = *(const short8*)(xb + ((size_t)i << 12) + (cc << 9));
      acc[cc] = __builtin_amdgcn_mfma_f32_16x16x32_bf16(av, bv, acc[cc], 0, 0, 0);
    }
  }
#pragma unroll
  for (int cc = 0; cc < 4; ++cc) *(f32x4*)&red[w][cc][l][0] = acc[cc];
  __syncthreads();
  // wave w owns cc = w after reduce
  f32x4 mm = (f32x4){0.f, 0.f, 0.f, 0.f};
#pragma unroll
  for (int wp = 0; wp < 4; ++wp) {
    f32x4 p = *(const f32x4*)&red[wp][w][l][0];
    mm[0] += p[0]; mm[1] += p[1]; mm[2] += p[2]; mm[3] += p[3];
  }
  size_t fo = (size_t)((rt << 3) + cf) * 64 + l;
  f32x4 yl = ((const f32x4*)YlabF)[fo];
  f32x4 xv = ((const f32x4*)XfPrev)[fo];
  f32x4 mult, rs;
#pragma unroll
  for (int r = 0; r < 4; ++r) {
    mult[r] = fmaf(xv[r], mm[r] + yl[r], xv[r]);
    rs[r] = mult[r];
  }
#pragma unroll
  for (int msk = 1; msk < 16; msk <<= 1) {
#pragma unroll
    for (int r = 0; r < 4; ++r) rs[r] += __shfl_xor(rs[r], msk);
  }
  int rg4 = l >> 4, col16 = l & 15;
  if (col16 == 0) {
#pragma unroll
    for (int r = 0; r < 4; ++r) sums_l[w][(rg4 << 2) + r] = rs[r];
  }
  __syncthreads();
  // wave 0: accumulate half-sums to global, then signal + spin for partner
  if (w == 0 && l < 16) {
    float hs = sums_l[0][l] + sums_l[1][l] + sums_l[2][l] + sums_l[3][l];
    atomicAdd(&sums2[(rt << 4) + l], hs);
  }
  if (t == 0) {
    asm volatile("s_waitcnt vmcnt(0)" ::: "memory");
    atomicAdd(&cnt2[rt], 1);
    while (atomicAdd(&cnt2[rt], 0) < 2) __builtin_amdgcn_s_sleep(2);
  }
  __syncthreads();
  if (w == 0 && l < 16) totl[l] = atomicAdd(&sums2[(rt << 4) + l], 0.0f) + 1e-8f;
  __syncthreads();
  f32x4 ov;
#pragma unroll
  for (int r = 0; r < 4; ++r) ov[r] = mult[r] / totl[(rg4 << 2) + r];
  ((f32x4*)XfOut)[fo] = ov;
  int kcp = rt >> 1;
  int rem = ((rt & 1) << 4) + (rg4 << 2);
  int khi = rem >> 3, k0 = rem & 7;
  ushort4 xo;
  xo.x = bf16rn(ov[0]); xo.y = bf16rn(ov[1]);
  xo.z = bf16rn(ov[2]); xo.w = bf16rn(ov[3]);
  *(ushort4*)&XpOut[((size_t)(((kcp << 3) + cf) << 2) + khi) * 128 + (col16 << 3) + k0] = xo;
}

// ---------------- output assembly ----------------
__global__ __launch_bounds__(256) void k_output(const float* __restrict__ Xf,
                                                const int* __restrict__ labels,
                                                float* __restrict__ out) {
  int idx = ((int)blockIdx.x << 8) + threadIdx.x;  // 409600
  int i = idx / NC, c = idx - i * NC;
  float v;
  if (i < NLAB) {
    v = (labels[i] == c) ? 1.0f : 0.0f;
  } else {
    int row = i - NLAB;
    int rt = row >> 4, r = row & 15;
    int rg4 = r >> 2, reg = r & 3;
    int cf = c >> 4, col = c & 15;
    v = Xf[((size_t)(((rt << 3) + cf) << 6) + (rg4 << 4) + col) * 4 + reg];
  }
  out[idx] = v;
}

extern "C" void kernel_launch(void* const* d_in, const int* in_sizes, int n_in,
                              void* d_out, int out_size, void* d_ws, size_t ws_size,
                              hipStream_t stream) {
  const float* E = (const float*)d_in[0];
  const int* labels = (const int*)d_in[1];
  float* out = (float*)d_out;
  char* ws = (char*)d_ws;
  const size_t MB = 1024 * 1024;

  float* A = (float*)ws;                          // 64 MB
  ushortT* Enh = (ushortT*)(ws + 64 * MB);        // 8 MB
  ushortT* Enl = (ushortT*)(ws + 72 * MB);        // 8 MB
  ushortT* ApL = (ushortT*)(ws + 80 * MB);        // 8 MB packed A[:, :2048]
  ushortT* ApU = (ushortT*)(ws + 88 * MB);        // 8 MB packed A[:, 2048:]
  float* sig = (float*)(ws + 96 * MB);
  double* parts = (double*)(ws + 96 * MB + 65536);
  float* meanb = (float*)(ws + 96 * MB + 131072);
  ushortT* Xlabp = (ushortT*)(ws + 97 * MB);      // 0.5 MB packed
  float* YlabF = (float*)(ws + 98 * MB);          // 1 MB frag-major
  float* Xf0 = (float*)(ws + 99 * MB);            // 1 MB frag-major
  float* Xf1 = (float*)(ws + 100 * MB);           // 1 MB
  ushortT* Xp0 = (ushortT*)(ws + 101 * MB);       // 0.5 MB packed
  ushortT* Xp1 = (ushortT*)(ws + 102 * MB);       // 0.5 MB
  float* Pp = (float*)(ws + 104 * MB);            // 4 MB (Ylab one-time)
  float* sums2 = (float*)(ws + 108 * MB);         // 30*128*16*4 = 240 KB
  int* cnt2 = (int*)(ws + 109 * MB);              // 30*128*4 = 15 KB

  k_normalize<<<NN, 256, 0, stream>>>(E, Enh, Enl);
  k_syrk_mfma<<<640, 256, 0, stream>>>(Enh, Enl, A);
  k_top7<<<NN / 4, 256, 0, stream>>>(A, sig);
  k_transform<<<NN, 256, 0, stream>>>(A, sig, parts);
  k_mean<<<1, 256, 0, stream>>>(parts, meanb);
  k_thresh_pack<<<8192, 256, 0, stream>>>(A, sig, meanb, ApL, ApU);
  k_xlabp<<<1024, 256, 0, stream>>>(labels, Xlabp);
  k_xinit<<<128, 64, 0, stream>>>(Xf0, Xp0);
  hipMemsetAsync(sums2, 0, (size_t)NITER * 128 * 16 * sizeof(float), stream);
  hipMemsetAsync(cnt2, 0, (size_t)NITER * 128 * sizeof(int), stream);
  k_gP<<<512, 256, 0, stream>>>(ApL, Xlabp, Pp);
  k_updY<<<128, 64, 0, stream>>>(Pp, YlabF);
  float* xf[2] = {Xf0, Xf1};
  ushortT* xp[2] = {Xp0, Xp1};
  int cur = 0;
  for (int it = 0; it < NITER; ++it) {
    int nxt = cur ^ 1;
    k_it2<<<256, 256, 0, stream>>>(ApU, xp[cur], YlabF, xf[cur], xf[nxt], xp[nxt],
                                   sums2 + (size_t)it * 2048, cnt2 + (size_t)it * 128);
    cur = nxt;
  }
  k_output<<<1600, 256, 0, stream>>>(xf[cur], labels, out);
}

// Round 12
// 428.824 us; speedup vs baseline: 1.6132x; 1.1157x over previous
//
#include <hip/hip_runtime.h>
#include <math.h>

typedef unsigned short ushortT;
typedef __attribute__((ext_vector_type(8))) short short8;
typedef __attribute__((ext_vector_type(4))) float f32x4;

#define NN 4096
#define DD 1024
#define NC 100
#define CP 128
#define NLAB 2048
#define NITER 30

__device__ __forceinline__ ushortT bf16rn(float x) {
  unsigned u = __float_as_uint(x);
  unsigned r = (u + 0x7fffu + ((u >> 16) & 1u)) >> 16;
  return (ushortT)r;
}
__device__ __forceinline__ float bf2f(ushortT h) {
  return __uint_as_float(((unsigned)h) << 16);
}
__device__ __forceinline__ void gload16(const void* g, void* l) {
  __builtin_amdgcn_global_load_lds((const __attribute__((address_space(1))) char*)g,
                                   (__attribute__((address_space(3))) char*)l, 16, 0, 0);
}

// ---------------- normalize rows -> bf16 ----------------
__global__ __launch_bounds__(256) void k_normalize(const float* __restrict__ E,
                                                   ushortT* __restrict__ Enh) {
  int row = blockIdx.x, t = threadIdx.x;
  const float4* e4 = (const float4*)(E + (size_t)row * DD);
  float4 v = e4[t];
  float ss = v.x * v.x + v.y * v.y + v.z * v.z + v.w * v.w;
  __shared__ float red[4];
  int lane = t & 63, w = t >> 6;
#pragma unroll
  for (int off = 32; off; off >>= 1) ss += __shfl_xor(ss, off);
  if (lane == 0) red[w] = ss;
  __syncthreads();
  float tot = red[0] + red[1] + red[2] + red[3];
  float d = fmaxf(sqrtf(tot), 1e-12f);
  ushort4 hv;
  hv.x = bf16rn(v.x / d); hv.y = bf16rn(v.y / d);
  hv.z = bf16rn(v.z / d); hv.w = bf16rn(v.w / d);
  ((ushort4*)Enh)[(size_t)row * 256 + t] = hv;
}

// ---------------- A0 = relu(En@En^T) pure bf16; diag=1; A stored bf16 ----------------
// Upper-tri tiles, XCD-banded; single-buffered 36 KB LDS -> 4 blocks/CU.
__global__ __launch_bounds__(256, 4) void k_syrk_mfma(const ushortT* __restrict__ Enh,
                                                      ushortT* __restrict__ A) {
  int xg = (int)blockIdx.x & 7;
  int j = (int)blockIdx.x >> 3;  // 0..79
  int bi = -1, bj = 0;
#pragma unroll
  for (int p = 0; p < 4; ++p) {
    int bic = xg + (p << 3);
    int c = 32 - bic;
    if (bi < 0) {
      if (j < c) { bi = bic; bj = bic + j; } else j -= c;
    }
  }
  if (bi < 0) return;
  __shared__ ushortT lds[18432];  // A-tile @0, B-tile @8192; f32 T overlay 34.8 KB
  int t = threadIdx.x;
  int l = t & 63, w = t >> 6;
  int i0 = bi << 7, j0 = bj << 7;
  int wr = w >> 1, wc = w & 1;
  f32x4 zz = {0.f, 0.f, 0.f, 0.f};
  f32x4 acc[4][4];
#pragma unroll
  for (int m = 0; m < 4; ++m)
#pragma unroll
    for (int n = 0; n < 4; ++n) acc[m][n] = zz;
  int arow_l = l & 15, kslot = l >> 4;

  for (int s = 0; s < 16; ++s) {
    int kk0 = s << 6;
#pragma unroll
    for (int q = 0; q < 4; ++q) {
      int n = (q << 8) + t;
      int r = n >> 3, p = n & 7;
      int col = (p ^ (r & 7)) << 3;
      gload16(Enh + (size_t)(i0 + r) * DD + kk0 + col, &lds[n << 3]);
      gload16(Enh + (size_t)(j0 + r) * DD + kk0 + col, &lds[8192 + (n << 3)]);
    }
    __syncthreads();
#pragma unroll
    for (int kk = 0; kk < 2; ++kk) {
      int g = (kk << 2) + kslot;
      short8 av[4], bv[4];
#pragma unroll
      for (int m = 0; m < 4; ++m) {
        int r = (wr << 6) + (m << 4) + arow_l;
        av[m] = *(const short8*)&lds[(r << 6) + ((g ^ (r & 7)) << 3)];
      }
#pragma unroll
      for (int n = 0; n < 4; ++n) {
        int r = (wc << 6) + (n << 4) + arow_l;
        bv[n] = *(const short8*)&lds[8192 + (r << 6) + ((g ^ (r & 7)) << 3)];
      }
#pragma unroll
      for (int m = 0; m < 4; ++m)
#pragma unroll
        for (int n = 0; n < 4; ++n)
          acc[m][n] = __builtin_amdgcn_mfma_f32_16x16x32_bf16(av[m], bv[n], acc[m][n], 0, 0, 0);
    }
    __syncthreads();
  }
  int rbase = (l >> 4) << 2;
#pragma unroll
  for (int m = 0; m < 4; ++m) {
#pragma unroll
    for (int n = 0; n < 4; ++n) {
#pragma unroll
      for (int r = 0; r < 4; ++r) {
        int gi = i0 + (wr << 6) + (m << 4) + rbase + r;
        int gj = j0 + (wc << 6) + (n << 4) + (l & 15);
        float v = fmaxf(acc[m][n][r], 0.0f);
        if (gi == gj) v = 1.0f;
        A[(size_t)gi * NN + gj] = bf16rn(v);
      }
    }
  }
  // mirror via LDS f32 transpose -> bf16 coalesced stores
  if (bi != bj) {
    float* T = (float*)&lds[0];
#pragma unroll
    for (int c2 = 0; c2 < 2; ++c2) {
      __syncthreads();
      if (wr == c2) {
#pragma unroll
        for (int m = 0; m < 4; ++m)
#pragma unroll
          for (int n = 0; n < 4; ++n)
#pragma unroll
            for (int r = 0; r < 4; ++r)
              T[(((wc << 6) + (n << 4) + (l & 15)) * 68) + (m << 4) + rbase + r] =
                  fmaxf(acc[m][n][r], 0.0f);
      }
      __syncthreads();
      int lj = t >> 1, cg = (t & 1) << 5;  // 32 cols per thread
#pragma unroll
      for (int q = 0; q < 4; ++q) {
        float4 a0 = *(const float4*)&T[lj * 68 + cg + (q << 3)];
        float4 a1 = *(const float4*)&T[lj * 68 + cg + (q << 3) + 4];
        short8 o;
        o[0] = (short)bf16rn(a0.x); o[1] = (short)bf16rn(a0.y);
        o[2] = (short)bf16rn(a0.z); o[3] = (short)bf16rn(a0.w);
        o[4] = (short)bf16rn(a1.x); o[5] = (short)bf16rn(a1.y);
        o[6] = (short)bf16rn(a1.z); o[7] = (short)bf16rn(a1.w);
        *(short8*)&A[(size_t)(j0 + lj) * NN + i0 + (c2 << 6) + cg + (q << 3)] = o;
      }
    }
  }
}

// ---------------- sigma[i] = 7th largest of row i (bf16 A) ----------------
__device__ __forceinline__ void ins7(float (&tv)[7], float v) {
  if (v > tv[6]) {
#pragma unroll
    for (int s = 0; s < 7; s++) {
      if (v > tv[s]) { float tmp = tv[s]; tv[s] = v; v = tmp; }
    }
  }
}
__global__ __launch_bounds__(256) void k_top7(const ushortT* __restrict__ A,
                                              float* __restrict__ sig) {
  int w = threadIdx.x >> 6, lane = threadIdx.x & 63;
  int row = (blockIdx.x << 2) + w;
  const ushortT* a = A + (size_t)row * NN;
  float tv[7];
#pragma unroll
  for (int i = 0; i < 7; i++) tv[i] = -1.0f;
#pragma unroll
  for (int k = 0; k < 8; k++) {
    short8 v = *(const short8*)(a + (k << 9) + (lane << 3));
#pragma unroll
    for (int jj = 0; jj < 8; jj++) ins7(tv, bf2f((ushortT)v[jj]));
  }
  int head = 0;
  float seventh = 0.0f;
  for (int r = 0; r < 7; r++) {
    float h = (head < 7) ? tv[head] : -1.0f;
    float m = h;
#pragma unroll
    for (int off = 32; off; off >>= 1) m = fmaxf(m, __shfl_xor(m, off));
    unsigned long long ball = __ballot(h == m);
    if (lane == (__ffsll(ball) - 1)) head++;
    seventh = m;
  }
  if (lane == 0) sig[row] = seventh;
}

// ---------------- mean pass over bf16 A ----------------
__global__ __launch_bounds__(256) void k_transform(const ushortT* __restrict__ A,
                                                   const float* __restrict__ sig,
                                                   double* __restrict__ parts) {
  int row = blockIdx.x;
  float si = sig[row];
  const ushortT* a = A + (size_t)row * NN;
  int t = threadIdx.x;
  double local = 0.0;
#pragma unroll
  for (int k = 0; k < 2; k++) {
    int idx = (k << 11) + (t << 3);
    short8 v = *(const short8*)(a + idx);
#pragma unroll
    for (int q = 0; q < 2; ++q) {
      float4 sg = *(const float4*)&sig[idx + (q << 2)];
      float s0 = bf2f((ushortT)v[(q << 2) + 0]);
      float s1 = bf2f((ushortT)v[(q << 2) + 1]);
      float s2 = bf2f((ushortT)v[(q << 2) + 2]);
      float s3 = bf2f((ushortT)v[(q << 2) + 3]);
      local += (double)expf(-(s0 * s0) / (si * sg.x)) +
               (double)expf(-(s1 * s1) / (si * sg.y)) +
               (double)expf(-(s2 * s2) / (si * sg.z)) +
               (double)expf(-(s3 * s3) / (si * sg.w));
    }
  }
  __shared__ double dred[4];
  int lane = t & 63, wv = t >> 6;
#pragma unroll
  for (int off = 32; off; off >>= 1) local += __shfl_xor(local, off);
  if (lane == 0) dred[wv] = local;
  __syncthreads();
  if (t == 0) parts[row] = dred[0] + dred[1] + dred[2] + dred[3];
}

__global__ __launch_bounds__(256) void k_mean(const double* __restrict__ parts,
                                              float* __restrict__ meanb) {
  int t = threadIdx.x;
  double local = 0.0;
#pragma unroll
  for (int k = 0; k < NN / 256; k++) local += parts[(k << 8) + t];
  __shared__ double dred[4];
  int lane = t & 63, wv = t >> 6;
#pragma unroll
  for (int off = 32; off; off >>= 1) local += __shfl_xor(local, off);
  if (lane == 0) dred[wv] = local;
  __syncthreads();
  if (t == 0) meanb[0] = (float)((dred[0] + dred[1] + dred[2] + dred[3]) / ((double)NN * (double)NN));
}

// ---------------- thresh: exp on bottom half (bf16 A), threshold, pack ----------------
__global__ __launch_bounds__(256) void k_thresh_pack(const ushortT* __restrict__ A,
                                                     const float* __restrict__ sig,
                                                     const float* __restrict__ meanb,
                                                     ushortT* __restrict__ ApL,
                                                     ushortT* __restrict__ ApU) {
  float m = meanb[0];
  int i8 = ((int)blockIdx.x << 8) + threadIdx.x;  // 1M over [2048][512 groups of 8]
  int row2 = i8 >> 9;
  int col8 = (i8 & 511) << 3;
  int grow = NLAB + row2;
  float si = sig[grow];
  short8 v = *(const short8*)&A[(size_t)grow * NN + col8];
  short8 o;
#pragma unroll
  for (int q = 0; q < 2; ++q) {
    float4 sg = *(const float4*)&sig[col8 + (q << 2)];
    float s0 = bf2f((ushortT)v[(q << 2) + 0]);
    float s1 = bf2f((ushortT)v[(q << 2) + 1]);
    float s2 = bf2f((ushortT)v[(q << 2) + 2]);
    float s3 = bf2f((ushortT)v[(q << 2) + 3]);
    float c0 = expf(-(s0 * s0) / (si * sg.x));
    float c1 = expf(-(s1 * s1) / (si * sg.y));
    float c2 = expf(-(s2 * s2) / (si * sg.z));
    float c3 = expf(-(s3 * s3) / (si * sg.w));
    o[(q << 2) + 0] = (short)((c0 < m) ? 0 : bf16rn(c0));
    o[(q << 2) + 1] = (short)((c1 < m) ? 0 : bf16rn(c1));
    o[(q << 2) + 2] = (short)((c2 < m) ? 0 : bf16rn(c2));
    o[(q << 2) + 3] = (short)((c3 < m) ? 0 : bf16rn(c3));
  }
  int half = col8 >> 11;
  int cc = col8 & 2047;
  int rt = row2 >> 4, arow = row2 & 15;
  int kc = cc >> 5, khi = (cc >> 3) & 3;
  ushortT* dst = half ? ApU : ApL;
  *(short8*)&dst[((size_t)((rt << 6) + kc) << 9) + (khi << 7) + (arow << 3)] = o;
}

// ---------------- one-hot labels, packed layout ----------------
__global__ __launch_bounds__(256) void k_xlabp(const int* __restrict__ labels,
                                               ushortT* __restrict__ Xlabp) {
  int idx = ((int)blockIdx.x << 8) + threadIdx.x;  // 262144
  int c = idx >> 11, j = idx & 2047;
  int kc = j >> 5, khi = (j >> 3) & 3, k0 = j & 7;
  int cf = c >> 4, slot = c & 15;
  Xlabp[((size_t)(((kc << 3) + cf) << 2) + khi) * 128 + (slot << 3) + k0] =
      (labels[j] == c) ? (ushortT)0x3F80 : (ushortT)0;
}

// ---------------- X init ----------------
__global__ __launch_bounds__(64) void k_xinit(float* __restrict__ Xf,
                                              ushortT* __restrict__ Xp) {
  int rt = blockIdx.x, l = threadIdx.x;
  int col = l & 15, rg4 = l >> 4;
  int kc = rt >> 1;
  int kk = ((rt & 1) << 4) + (rg4 << 2);
  int khi = kk >> 3, k0 = kk & 7;
#pragma unroll
  for (int cf = 0; cf < 8; ++cf) {
    int cls = (cf << 4) + col;
    float v = (cls < NC) ? 0.01f : 0.0f;
    ((f32x4*)Xf)[(size_t)((rt << 3) + cf) * 64 + l] = (f32x4){v, v, v, v};
    ushortT h = bf16rn(v);
    ushort4 hv = {h, h, h, h};
    *(ushort4*)&Xp[((size_t)(((kc << 3) + cf) << 2) + khi) * 128 + (col << 3) + k0] = hv;
  }
}

// ---------------- Ylab path: partial GEMM + reduce (one-time) ----------------
__global__ __launch_bounds__(256) void k_gP(const ushortT* __restrict__ Ap,
                                            const ushortT* __restrict__ Xp,
                                            float* __restrict__ Pp) {
  int t = threadIdx.x, l = t & 63, w = t >> 6;
  int bid = (int)blockIdx.x;
  int rt = ((bid & 7) << 4) + ((bid >> 3) & 15);
  int s = bid >> 7;  // 0..3
  int kc0 = (s << 4) + (w << 2);
  const ushortT* ab = Ap + ((size_t)rt << 15) + ((size_t)kc0 << 9) + (l << 3);
  const ushortT* xb = Xp + ((size_t)kc0 << 12) + (l << 3);
  short8 av[4];
#pragma unroll
  for (int i = 0; i < 4; ++i) av[i] = *(const short8*)(ab + ((size_t)i << 9));
  f32x4 acc[8];
#pragma unroll
  for (int cf = 0; cf < 8; ++cf) {
    acc[cf] = (f32x4){0.f, 0.f, 0.f, 0.f};
#pragma unroll
    for (int i = 0; i < 4; ++i) {
      short8 bv = *(const short8*)(xb + ((size_t)i << 12) + (cf << 9));
      acc[cf] = __builtin_amdgcn_mfma_f32_16x16x32_bf16(av[i], bv, acc[cf], 0, 0, 0);
    }
  }
  __shared__ float red[4][8][64][4];  // 32 KB
#pragma unroll
  for (int cf = 0; cf < 8; ++cf) *(f32x4*)&red[w][cf][l][0] = acc[cf];
  __syncthreads();
  if (w < 2) {
#pragma unroll
    for (int q = 0; q < 4; ++q) {
      int cf = (w << 2) + q;
      f32x4 sum = *(const f32x4*)&red[0][cf][l][0];
#pragma unroll
      for (int wp = 1; wp < 4; ++wp) {
        f32x4 p = *(const f32x4*)&red[wp][cf][l][0];
        sum[0] += p[0]; sum[1] += p[1]; sum[2] += p[2]; sum[3] += p[3];
      }
      ((f32x4*)Pp)[((size_t)(((s << 7) + rt) << 3) + cf) * 64 + l] = sum;
    }
  }
}

__global__ __launch_bounds__(64) void k_updY(const float* __restrict__ Pp,
                                             float* __restrict__ YlabF) {
  int rt = blockIdx.x, l = threadIdx.x;
#pragma unroll
  for (int cf = 0; cf < 8; ++cf) {
    f32x4 acc = (f32x4){0.f, 0.f, 0.f, 0.f};
#pragma unroll
    for (int s = 0; s < 4; ++s) {
      f32x4 p = ((const f32x4*)Pp)[((size_t)(((s << 7) + rt) << 3) + cf) * 64 + l];
      acc[0] += p[0]; acc[1] += p[1]; acc[2] += p[2]; acc[3] += p[3];
    }
    ((f32x4*)YlabF)[(size_t)((rt << 3) + cf) * 64 + l] = acc;
  }
}

// ---------------- fused iteration, ONE launch: 256 blocks = 128 rt x 2 cf-halves ---
__global__ __launch_bounds__(256) void k_it2(
    const ushortT* __restrict__ Ap, const ushortT* __restrict__ Xp,
    const float* __restrict__ YlabF, const float* __restrict__ XfPrev,
    float* __restrict__ XfOut, ushortT* __restrict__ XpOut,
    float* __restrict__ sums2, int* __restrict__ cnt2) {
  __shared__ float red[4][4][64][4];  // 16 KB
  __shared__ float sums_l[4][16];
  __shared__ float totl[16];
  int t = threadIdx.x, l = t & 63, w = t >> 6;
  int bid = (int)blockIdx.x;
  int rt = ((bid & 7) << 4) + ((bid >> 3) & 15);
  int half = bid >> 7;
  int cf = (half << 2) + w;

  const ushortT* ab = Ap + ((size_t)rt << 15) + ((size_t)(w << 4) << 9) + (l << 3);
  const ushortT* xb = Xp + ((size_t)(w << 4) << 12) + ((size_t)(half << 2) << 9) + (l << 3);
  f32x4 acc[4];
#pragma unroll
  for (int cc = 0; cc < 4; ++cc) acc[cc] = (f32x4){0.f, 0.f, 0.f, 0.f};
#pragma unroll
  for (int i = 0; i < 16; ++i) {
    short8 av = *(const short8*)(ab + ((size_t)i << 9));
#pragma unroll
    for (int cc = 0; cc < 4; ++cc) {
      short8 bv = *(const short8*)(xb + ((size_t)i << 12) + (cc << 9));
      acc[cc] = __builtin_amdgcn_mfma_f32_16x16x32_bf16(av, bv, acc[cc], 0, 0, 0);
    }
  }
#pragma unroll
  for (int cc = 0; cc < 4; ++cc) *(f32x4*)&red[w][cc][l][0] = acc[cc];
  __syncthreads();
  f32x4 mm = (f32x4){0.f, 0.f, 0.f, 0.f};
#pragma unroll
  for (int wp = 0; wp < 4; ++wp) {
    f32x4 p = *(const f32x4*)&red[wp][w][l][0];
    mm[0] += p[0]; mm[1] += p[1]; mm[2] += p[2]; mm[3] += p[3];
  }
  size_t fo = (size_t)((rt << 3) + cf) * 64 + l;
  f32x4 yl = ((const f32x4*)YlabF)[fo];
  f32x4 xv = ((const f32x4*)XfPrev)[fo];
  f32x4 mult, rs;
#pragma unroll
  for (int r = 0; r < 4; ++r) {
    mult[r] = fmaf(xv[r], mm[r] + yl[r], xv[r]);
    rs[r] = mult[r];
  }
#pragma unroll
  for (int msk = 1; msk < 16; msk <<= 1) {
#pragma unroll
    for (int r = 0; r < 4; ++r) rs[r] += __shfl_xor(rs[r], msk);
  }
  int rg4 = l >> 4, col16 = l & 15;
  if (col16 == 0) {
#pragma unroll
    for (int r = 0; r < 4; ++r) sums_l[w][(rg4 << 2) + r] = rs[r];
  }
  __syncthreads();
  if (w == 0 && l < 16) {
    float hs = sums_l[0][l] + sums_l[1][l] + sums_l[2][l] + sums_l[3][l];
    atomicAdd(&sums2[(rt << 4) + l], hs);
  }
  if (t == 0) {
    asm volatile("s_waitcnt vmcnt(0)" ::: "memory");
    atomicAdd(&cnt2[rt], 1);
    while (atomicAdd(&cnt2[rt], 0) < 2) __builtin_amdgcn_s_sleep(2);
  }
  __syncthreads();
  if (w == 0 && l < 16) totl[l] = atomicAdd(&sums2[(rt << 4) + l], 0.0f) + 1e-8f;
  __syncthreads();
  f32x4 ov;
#pragma unroll
  for (int r = 0; r < 4; ++r) ov[r] = mult[r] / totl[(rg4 << 2) + r];
  ((f32x4*)XfOut)[fo] = ov;
  int kcp = rt >> 1;
  int rem = ((rt & 1) << 4) + (rg4 << 2);
  int khi = rem >> 3, k0 = rem & 7;
  ushort4 xo;
  xo.x = bf16rn(ov[0]); xo.y = bf16rn(ov[1]);
  xo.z = bf16rn(ov[2]); xo.w = bf16rn(ov[3]);
  *(ushort4*)&XpOut[((size_t)(((kcp << 3) + cf) << 2) + khi) * 128 + (col16 << 3) + k0] = xo;
}

// ---------------- output assembly ----------------
__global__ __launch_bounds__(256) void k_output(const float* __restrict__ Xf,
                                                const int* __restrict__ labels,
                                                float* __restrict__ out) {
  int idx = ((int)blockIdx.x << 8) + threadIdx.x;  // 409600
  int i = idx / NC, c = idx - i * NC;
  float v;
  if (i < NLAB) {
    v = (labels[i] == c) ? 1.0f : 0.0f;
  } else {
    int row = i - NLAB;
    int rt = row >> 4, r = row & 15;
    int rg4 = r >> 2, reg = r & 3;
    int cf = c >> 4, col = c & 15;
    v = Xf[((size_t)(((rt << 3) + cf) << 6) + (rg4 << 4) + col) * 4 + reg];
  }
  out[idx] = v;
}

extern "C" void kernel_launch(void* const* d_in, const int* in_sizes, int n_in,
                              void* d_out, int out_size, void* d_ws, size_t ws_size,
                              hipStream_t stream) {
  const float* E = (const float*)d_in[0];
  const int* labels = (const int*)d_in[1];
  float* out = (float*)d_out;
  char* ws = (char*)d_ws;
  const size_t MB = 1024 * 1024;

  ushortT* A = (ushortT*)ws;                      // 32 MB bf16 [4096][4096]
  ushortT* Enh = (ushortT*)(ws + 32 * MB);        // 8 MB
  ushortT* ApL = (ushortT*)(ws + 40 * MB);        // 8 MB packed A[:, :2048]
  ushortT* ApU = (ushortT*)(ws + 48 * MB);        // 8 MB packed A[:, 2048:]
  float* sig = (float*)(ws + 56 * MB);
  double* parts = (double*)(ws + 56 * MB + 65536);
  float* meanb = (float*)(ws + 56 * MB + 131072);
  ushortT* Xlabp = (ushortT*)(ws + 57 * MB);      // 0.5 MB packed
  float* YlabF = (float*)(ws + 58 * MB);          // 1 MB frag-major
  float* Xf0 = (float*)(ws + 59 * MB);            // 1 MB
  float* Xf1 = (float*)(ws + 60 * MB);            // 1 MB
  ushortT* Xp0 = (ushortT*)(ws + 61 * MB);        // 0.5 MB
  ushortT* Xp1 = (ushortT*)(ws + 62 * MB);        // 0.5 MB
  float* Pp = (float*)(ws + 64 * MB);             // 4 MB (Ylab one-time)
  float* sums2 = (float*)(ws + 68 * MB);          // 240 KB
  int* cnt2 = (int*)(ws + 69 * MB);               // 15 KB

  k_normalize<<<NN, 256, 0, stream>>>(E, Enh);
  k_syrk_mfma<<<640, 256, 0, stream>>>(Enh, A);
  k_top7<<<NN / 4, 256, 0, stream>>>(A, sig);
  k_transform<<<NN, 256, 0, stream>>>(A, sig, parts);
  k_mean<<<1, 256, 0, stream>>>(parts, meanb);
  k_thresh_pack<<<4096, 256, 0, stream>>>(A, sig, meanb, ApL, ApU);
  k_xlabp<<<1024, 256, 0, stream>>>(labels, Xlabp);
  k_xinit<<<128, 64, 0, stream>>>(Xf0, Xp0);
  hipMemsetAsync(sums2, 0, (size_t)NITER * 128 * 16 * sizeof(float), stream);
  hipMemsetAsync(cnt2, 0, (size_t)NITER * 128 * sizeof(int), stream);
  k_gP<<<512, 256, 0, stream>>>(ApL, Xlabp, Pp);
  k_updY<<<128, 64, 0, stream>>>(Pp, YlabF);
  float* xf[2] = {Xf0, Xf1};
  ushortT* xp[2] = {Xp0, Xp1};
  int cur = 0;
  for (int it = 0; it < NITER; ++it) {
    int nxt = cur ^ 1;
    k_it2<<<256, 256, 0, stream>>>(ApU, xp[cur], YlabF, xf[cur], xf[nxt], xp[nxt],
                                   sums2 + (size_t)it * 2048, cnt2 + (size_t)it * 128);
    cur = nxt;
  }
  k_output<<<1600, 256, 0, stream>>>(xf[cur], labels, out);
}